// Round 1
// baseline (6136.144 us; speedup 1.0000x reference)
//
#include <hip/hip_runtime.h>
#include <math.h>

#define N_NODES 100000
#define N_EDGES 1600000
#define IN_C 128
#define HID_C 128
#define OUT_C 64
#define NLAYERS 4
#define KSTEPS 10
#define ALPHA 0.1f
#define LN_EPS 1e-5f

__device__ __forceinline__ float gelu_exact(float x) {
    // jax.nn.gelu(approximate=False) = 0.5*x*(1+erf(x/sqrt(2)))
    return 0.5f * x * (1.0f + erff(x * 0.70710678118654752f));
}

// ---------------------------------------------------------------------------
// CSR build: count in-degree per dst
__global__ void count_k(const int* __restrict__ dst, int* __restrict__ counts) {
    int e = blockIdx.x * blockDim.x + threadIdx.x;
    if (e < N_EDGES) atomicAdd(&counts[dst[e]], 1);
}

// Single-block exclusive scan over counts[0..N_NODES] -> row_off / fill_pos
__global__ void scan_k(const int* __restrict__ counts,
                       int* __restrict__ row_off,
                       int* __restrict__ fill_pos) {
    const int n = N_NODES + 1;
    __shared__ int s[1024];
    int t = threadIdx.x;
    const int CH = (n + 1023) >> 10;          // elems per thread
    int b = t * CH;
    int e = min(b + CH, n);
    int sum = 0;
    for (int i = b; i < e; ++i) sum += counts[i];
    s[t] = sum;
    __syncthreads();
    // Hillis-Steele inclusive scan over 1024 partials
    for (int off = 1; off < 1024; off <<= 1) {
        int v = (t >= off) ? s[t - off] : 0;
        __syncthreads();
        s[t] += v;
        __syncthreads();
    }
    int run = (t == 0) ? 0 : s[t - 1];        // exclusive prefix for this chunk
    for (int i = b; i < e; ++i) {
        row_off[i] = run;
        fill_pos[i] = run;
        run += counts[i];
    }
}

// Bucket edges by dst; pack (src, (1-alpha)*w) into int2
__global__ void bucket_k(const int* __restrict__ src, const int* __restrict__ dst,
                         const float* __restrict__ w,
                         int* __restrict__ fill_pos, int2* __restrict__ ep) {
    int e = blockIdx.x * blockDim.x + threadIdx.x;
    if (e >= N_EDGES) return;
    int d = dst[e];
    int pos = atomicAdd(&fill_pos[d], 1);
    float ws = (1.0f - ALPHA) * w[e];
    ep[pos] = make_int2(src[e], __float_as_int(ws));
}

// ---------------------------------------------------------------------------
// Encoder: H = gelu(LN(x @ Wenc^T)).  Wave per row; lane holds channels (2l, 2l+1).
__global__ __launch_bounds__(256) void encoder_k(
        const float* __restrict__ x, const float* __restrict__ Wenc,
        const float* __restrict__ gamma, const float* __restrict__ beta,
        float* __restrict__ H) {
    __shared__ float WT[IN_C * HID_C];        // WT[k*128 + c] = Wenc[c*128 + k]
    for (int i = threadIdx.x; i < IN_C * HID_C; i += 256) {
        int c = i >> 7, k = i & 127;
        WT[k * HID_C + c] = Wenc[i];
    }
    __syncthreads();
    int lane = threadIdx.x & 63;
    int wid  = threadIdx.x >> 6;
    float2 gb = ((const float2*)gamma)[lane];
    float2 bb = ((const float2*)beta)[lane];
    const float2* WT2 = (const float2*)WT;
    for (int row = blockIdx.x * 4 + wid; row < N_NODES; row += gridDim.x * 4) {
        const float* xr = x + (size_t)row * IN_C;
        float ax = 0.f, ay = 0.f;
#pragma unroll 4
        for (int k = 0; k < IN_C; ++k) {
            float xk = xr[k];                  // wave-uniform, L1 broadcast
            float2 wv = WT2[k * 64 + lane];
            ax = fmaf(xk, wv.x, ax);
            ay = fmaf(xk, wv.y, ay);
        }
        // LayerNorm over 128 channels (2 per lane, 64 lanes)
        float sum = ax + ay;
        for (int off = 32; off; off >>= 1) sum += __shfl_xor(sum, off);
        float mu = sum * (1.0f / 128.0f);
        float dx = ax - mu, dy = ay - mu;
        float vs = dx * dx + dy * dy;
        for (int off = 32; off; off >>= 1) vs += __shfl_xor(vs, off);
        float inv = rsqrtf(vs * (1.0f / 128.0f) + LN_EPS);
        float2 o;
        o.x = gelu_exact(gb.x * dx * inv + bb.x);
        o.y = gelu_exact(gb.y * dy * inv + bb.y);
        ((float2*)H)[(size_t)row * 64 + lane] = o;
    }
}

// ---------------------------------------------------------------------------
// One APPNP step (pull): zout[n] = alpha*x0[n] + sum_{e into n} w'_e * zin[src_e]
// Wave per node; lane holds channels (2l, 2l+1) as float2.
__global__ __launch_bounds__(256) void prop_k(
        const float* __restrict__ zin, const float* __restrict__ x0,
        const int* __restrict__ row_off, const int2* __restrict__ ep,
        float* __restrict__ zout) {
    int gw = (blockIdx.x * 256 + threadIdx.x) >> 6;   // node id
    if (gw >= N_NODES) return;
    int lane = threadIdx.x & 63;
    int s0 = row_off[gw];
    int s1 = row_off[gw + 1];
    const float2* z2 = (const float2*)zin;
    float2 xv = ((const float2*)x0)[gw * 64 + lane];
    float sx = 0.f, sy = 0.f;
    int e = s0;
    for (; e + 1 < s1; e += 2) {                       // 2 gathers in flight
        int2 p0 = ep[e];
        int2 p1 = ep[e + 1];
        float2 z0 = z2[p0.x * 64 + lane];
        float2 z1 = z2[p1.x * 64 + lane];
        float w0 = __int_as_float(p0.y);
        float w1 = __int_as_float(p1.y);
        sx = fmaf(w0, z0.x, sx); sy = fmaf(w0, z0.y, sy);
        sx = fmaf(w1, z1.x, sx); sy = fmaf(w1, z1.y, sy);
    }
    if (e < s1) {
        int2 p = ep[e];
        float2 z0 = z2[p.x * 64 + lane];
        float w = __int_as_float(p.y);
        sx = fmaf(w, z0.x, sx); sy = fmaf(w, z0.y, sy);
    }
    float2 o;
    o.x = fmaf(ALPHA, xv.x, sx);
    o.y = fmaf(ALPHA, xv.y, sy);
    ((float2*)zout)[gw * 64 + lane] = o;
}

// ---------------------------------------------------------------------------
// Post-APPNP: H = LN(gelu(z)).  Wave per row; lane holds channels (2l, 2l+1).
__global__ __launch_bounds__(256) void gelu_ln_k(
        const float* __restrict__ z, const float* __restrict__ gamma,
        const float* __restrict__ beta, float* __restrict__ H) {
    int gw = (blockIdx.x * 256 + threadIdx.x) >> 6;
    if (gw >= N_NODES) return;
    int lane = threadIdx.x & 63;
    float2 zv = ((const float2*)z)[gw * 64 + lane];
    float h0 = gelu_exact(zv.x);
    float h1 = gelu_exact(zv.y);
    float sum = h0 + h1;
    for (int off = 32; off; off >>= 1) sum += __shfl_xor(sum, off);
    float mu = sum * (1.0f / 128.0f);
    float d0 = h0 - mu, d1 = h1 - mu;
    float vs = d0 * d0 + d1 * d1;
    for (int off = 32; off; off >>= 1) vs += __shfl_xor(vs, off);
    float inv = rsqrtf(vs * (1.0f / 128.0f) + LN_EPS);
    float2 gb = ((const float2*)gamma)[lane];
    float2 bb = ((const float2*)beta)[lane];
    float2 o;
    o.x = gb.x * d0 * inv + bb.x;
    o.y = gb.y * d1 * inv + bb.y;
    ((float2*)H)[gw * 64 + lane] = o;
}

// ---------------------------------------------------------------------------
// Decoder: out = H @ Wdec^T  -> [N, 64].  Wave per row; lane = output channel.
__global__ __launch_bounds__(256) void decoder_k(
        const float* __restrict__ H, const float* __restrict__ Wdec,
        float* __restrict__ out) {
    __shared__ float WT[HID_C * OUT_C];       // WT[k*64 + o] = Wdec[o*128 + k]
    for (int i = threadIdx.x; i < OUT_C * HID_C; i += 256) {
        int o = i >> 7, k = i & 127;
        WT[k * OUT_C + o] = Wdec[i];
    }
    __syncthreads();
    int lane = threadIdx.x & 63;
    int wid  = threadIdx.x >> 6;
    for (int row = blockIdx.x * 4 + wid; row < N_NODES; row += gridDim.x * 4) {
        const float* hr = H + (size_t)row * HID_C;
        float acc = 0.f;
#pragma unroll 4
        for (int k = 0; k < HID_C; ++k) {
            acc = fmaf(hr[k], WT[k * OUT_C + lane], acc);
        }
        out[(size_t)row * OUT_C + lane] = acc;
    }
}

// ---------------------------------------------------------------------------
extern "C" void kernel_launch(void* const* d_in, const int* in_sizes, int n_in,
                              void* d_out, int out_size, void* d_ws, size_t ws_size,
                              hipStream_t stream) {
    const float* x     = (const float*)d_in[0];
    const int*   ei    = (const int*)d_in[1];   // [2, E] int32
    const float* ew    = (const float*)d_in[2];
    const float* Wenc  = (const float*)d_in[3];
    const float* Wdec  = (const float*)d_in[4];
    const float* gamma = (const float*)d_in[5];
    const float* beta  = (const float*)d_in[6];
    float* out = (float*)d_out;

    const int* src = ei;
    const int* dst = ei + N_EDGES;

    char* p = (char*)d_ws;
    auto carve = [&](size_t bytes) -> void* {
        void* r = (void*)p;
        p += (bytes + 255) & ~(size_t)255;
        return r;
    };
    int*  counts  = (int*)carve((N_NODES + 1) * sizeof(int));
    int*  fillpos = (int*)carve((N_NODES + 1) * sizeof(int));
    int*  row_off = (int*)carve((N_NODES + 1) * sizeof(int));
    int2* ep      = (int2*)carve((size_t)N_EDGES * sizeof(int2));
    float* H  = (float*)carve((size_t)N_NODES * HID_C * sizeof(float));
    float* ZA = (float*)carve((size_t)N_NODES * HID_C * sizeof(float));
    float* ZB = (float*)carve((size_t)N_NODES * HID_C * sizeof(float));

    // CSR build (per launch; deterministic work each call)
    hipMemsetAsync(counts, 0, (N_NODES + 1) * sizeof(int), stream);
    count_k<<<(N_EDGES + 255) / 256, 256, 0, stream>>>(dst, counts);
    scan_k<<<1, 1024, 0, stream>>>(counts, row_off, fillpos);
    bucket_k<<<(N_EDGES + 255) / 256, 256, 0, stream>>>(src, dst, ew, fillpos, ep);

    // Encoder
    encoder_k<<<512, 256, 0, stream>>>(x, Wenc, gamma, beta, H);

    const int node_blocks = (N_NODES + 3) / 4;   // 4 waves (rows) per 256-block
    float* bufs[2] = {ZA, ZB};
    for (int l = 0; l < NLAYERS; ++l) {
        const float* zin = H;                     // x0 = H (layer input)
        for (int k = 0; k < KSTEPS; ++k) {
            float* zout = bufs[k & 1];
            prop_k<<<node_blocks, 256, 0, stream>>>(zin, H, row_off, ep, zout);
            zin = zout;
        }
        gelu_ln_k<<<node_blocks, 256, 0, stream>>>(zin, gamma, beta, H);
    }

    decoder_k<<<1024, 256, 0, stream>>>(H, Wdec, out);
}

// Round 2
// 5667.546 us; speedup vs baseline: 1.0827x; 1.0827x over previous
//
#include <hip/hip_runtime.h>
#include <math.h>

#define N_NODES 100000
#define N_EDGES 1600000
#define IN_C 128
#define HID_C 128
#define OUT_C 64
#define NLAYERS 4
#define KSTEPS 10
#define ALPHA 0.1f
#define LN_EPS 1e-5f

__device__ __forceinline__ float gelu_exact(float x) {
    // jax.nn.gelu(approximate=False) = 0.5*x*(1+erf(x/sqrt(2)))
    return 0.5f * x * (1.0f + erff(x * 0.70710678118654752f));
}

// ---------------------------------------------------------------------------
// CSR build: count in-degree per dst
__global__ void count_k(const int* __restrict__ dst, int* __restrict__ counts) {
    int e = blockIdx.x * blockDim.x + threadIdx.x;
    if (e < N_EDGES) atomicAdd(&counts[dst[e]], 1);
}

// Single-block exclusive scan over counts[0..N_NODES] -> row_off / fill_pos
__global__ void scan_k(const int* __restrict__ counts,
                       int* __restrict__ row_off,
                       int* __restrict__ fill_pos) {
    const int n = N_NODES + 1;
    __shared__ int s[1024];
    int t = threadIdx.x;
    const int CH = (n + 1023) >> 10;          // elems per thread
    int b = t * CH;
    int e = min(b + CH, n);
    int sum = 0;
    for (int i = b; i < e; ++i) sum += counts[i];
    s[t] = sum;
    __syncthreads();
    for (int off = 1; off < 1024; off <<= 1) {
        int v = (t >= off) ? s[t - off] : 0;
        __syncthreads();
        s[t] += v;
        __syncthreads();
    }
    int run = (t == 0) ? 0 : s[t - 1];        // exclusive prefix for this chunk
    for (int i = b; i < e; ++i) {
        row_off[i] = run;
        fill_pos[i] = run;
        run += counts[i];
    }
}

// Bucket edges by dst; pack (src, (1-alpha)*w) into int2
__global__ void bucket_k(const int* __restrict__ src, const int* __restrict__ dst,
                         const float* __restrict__ w,
                         int* __restrict__ fill_pos, int2* __restrict__ ep) {
    int e = blockIdx.x * blockDim.x + threadIdx.x;
    if (e >= N_EDGES) return;
    int d = dst[e];
    int pos = atomicAdd(&fill_pos[d], 1);
    float ws = (1.0f - ALPHA) * w[e];
    ep[pos] = make_int2(src[e], __float_as_int(ws));
}

// ---------------------------------------------------------------------------
// LN(+gelu) epilogue for one row; lane holds channels (lane, lane+64).
__device__ __forceinline__ void ln_gelu_store(float a0, float a1,
                                              float g0, float g1, float b0, float b1,
                                              float* __restrict__ Hrow, int lane) {
    float sum = a0 + a1;
    for (int off = 32; off; off >>= 1) sum += __shfl_xor(sum, off);
    float mu = sum * (1.0f / 128.0f);
    float d0 = a0 - mu, d1 = a1 - mu;
    float vs = d0 * d0 + d1 * d1;
    for (int off = 32; off; off >>= 1) vs += __shfl_xor(vs, off);
    float inv = rsqrtf(vs * (1.0f / 128.0f) + LN_EPS);
    Hrow[lane]      = gelu_exact(g0 * d0 * inv + b0);
    Hrow[64 + lane] = gelu_exact(g1 * d1 * inv + b1);
}

// Encoder: H = gelu(LN(x @ Wenc^T)).
// block=1024 (16 waves); wave handles 4 rows; lane holds out-channels (l, l+64).
// WT padded to 129 floats/row: staging writes and both reads are <=2-way (free).
__global__ __launch_bounds__(1024) void encoder_k(
        const float* __restrict__ x, const float* __restrict__ Wenc,
        const float* __restrict__ gamma, const float* __restrict__ beta,
        float* __restrict__ H) {
    __shared__ float WT[IN_C * (HID_C + 1)];   // WT[k*129 + c] = Wenc[c*128 + k]
    for (int i = threadIdx.x; i < IN_C * HID_C; i += 1024) {
        int c = i >> 7, k = i & 127;
        WT[k * 129 + c] = Wenc[i];
    }
    __syncthreads();
    int lane = threadIdx.x & 63;
    int wid  = threadIdx.x >> 6;               // 0..15
    float g0 = gamma[lane], g1 = gamma[lane + 64];
    float b0 = beta[lane],  b1 = beta[lane + 64];
    int wstride = gridDim.x * 16;
    for (int grp = blockIdx.x * 16 + wid; grp * 4 < N_NODES; grp += wstride) {
        int r0 = grp * 4;                      // N_NODES % 4 == 0, rows r0..r0+3 valid
        const float* xp = x + (size_t)r0 * IN_C;
        float a00 = 0, a01 = 0, a10 = 0, a11 = 0;
        float a20 = 0, a21 = 0, a30 = 0, a31 = 0;
#pragma unroll 8
        for (int k = 0; k < IN_C; ++k) {
            float w0 = WT[k * 129 + lane];
            float w1 = WT[k * 129 + 64 + lane];
            float x0k = xp[k];
            float x1k = xp[IN_C + k];
            float x2k = xp[2 * IN_C + k];
            float x3k = xp[3 * IN_C + k];
            a00 = fmaf(x0k, w0, a00); a01 = fmaf(x0k, w1, a01);
            a10 = fmaf(x1k, w0, a10); a11 = fmaf(x1k, w1, a11);
            a20 = fmaf(x2k, w0, a20); a21 = fmaf(x2k, w1, a21);
            a30 = fmaf(x3k, w0, a30); a31 = fmaf(x3k, w1, a31);
        }
        ln_gelu_store(a00, a01, g0, g1, b0, b1, H + (size_t)r0 * HID_C,       lane);
        ln_gelu_store(a10, a11, g0, g1, b0, b1, H + (size_t)(r0 + 1) * HID_C, lane);
        ln_gelu_store(a20, a21, g0, g1, b0, b1, H + (size_t)(r0 + 2) * HID_C, lane);
        ln_gelu_store(a30, a31, g0, g1, b0, b1, H + (size_t)(r0 + 3) * HID_C, lane);
    }
}

// ---------------------------------------------------------------------------
// One APPNP step (pull): zout[n] = alpha*x0[n] + sum_{e into n} w'_e * zin[src_e]
// Wave per node; lane holds channels (2l, 2l+1) as float2; 4 gathers in flight.
__global__ __launch_bounds__(256) void prop_k(
        const float* __restrict__ zin, const float* __restrict__ x0,
        const int* __restrict__ row_off, const int2* __restrict__ ep,
        float* __restrict__ zout) {
    int gw = (blockIdx.x * 256 + threadIdx.x) >> 6;   // node id
    if (gw >= N_NODES) return;
    int lane = threadIdx.x & 63;
    int s0 = row_off[gw];
    int s1 = row_off[gw + 1];
    const float2* z2 = (const float2*)zin;
    float2 xv = ((const float2*)x0)[(size_t)gw * 64 + lane];
    float sx = 0.f, sy = 0.f;
    int e = s0;
    for (; e + 3 < s1; e += 4) {                       // 4 row-gathers in flight
        int2 p0 = ep[e];
        int2 p1 = ep[e + 1];
        int2 p2 = ep[e + 2];
        int2 p3 = ep[e + 3];
        float2 z0 = z2[(size_t)p0.x * 64 + lane];
        float2 z1 = z2[(size_t)p1.x * 64 + lane];
        float2 zz2 = z2[(size_t)p2.x * 64 + lane];
        float2 z3 = z2[(size_t)p3.x * 64 + lane];
        float w0 = __int_as_float(p0.y);
        float w1 = __int_as_float(p1.y);
        float w2 = __int_as_float(p2.y);
        float w3 = __int_as_float(p3.y);
        sx = fmaf(w0, z0.x, sx);  sy = fmaf(w0, z0.y, sy);
        sx = fmaf(w1, z1.x, sx);  sy = fmaf(w1, z1.y, sy);
        sx = fmaf(w2, zz2.x, sx); sy = fmaf(w2, zz2.y, sy);
        sx = fmaf(w3, z3.x, sx);  sy = fmaf(w3, z3.y, sy);
    }
    for (; e < s1; ++e) {
        int2 p = ep[e];
        float2 z0 = z2[(size_t)p.x * 64 + lane];
        float w = __int_as_float(p.y);
        sx = fmaf(w, z0.x, sx); sy = fmaf(w, z0.y, sy);
    }
    float2 o;
    o.x = fmaf(ALPHA, xv.x, sx);
    o.y = fmaf(ALPHA, xv.y, sy);
    ((float2*)zout)[(size_t)gw * 64 + lane] = o;
}

// ---------------------------------------------------------------------------
// Post-APPNP: H = LN(gelu(z)).  Wave per row; lane holds channels (2l, 2l+1).
__global__ __launch_bounds__(256) void gelu_ln_k(
        const float* __restrict__ z, const float* __restrict__ gamma,
        const float* __restrict__ beta, float* __restrict__ H) {
    int gw = (blockIdx.x * 256 + threadIdx.x) >> 6;
    if (gw >= N_NODES) return;
    int lane = threadIdx.x & 63;
    float2 zv = ((const float2*)z)[(size_t)gw * 64 + lane];
    float h0 = gelu_exact(zv.x);
    float h1 = gelu_exact(zv.y);
    float sum = h0 + h1;
    for (int off = 32; off; off >>= 1) sum += __shfl_xor(sum, off);
    float mu = sum * (1.0f / 128.0f);
    float d0 = h0 - mu, d1 = h1 - mu;
    float vs = d0 * d0 + d1 * d1;
    for (int off = 32; off; off >>= 1) vs += __shfl_xor(vs, off);
    float inv = rsqrtf(vs * (1.0f / 128.0f) + LN_EPS);
    float2 gb = ((const float2*)gamma)[lane];
    float2 bb = ((const float2*)beta)[lane];
    float2 o;
    o.x = gb.x * d0 * inv + bb.x;
    o.y = gb.y * d1 * inv + bb.y;
    ((float2*)H)[(size_t)gw * 64 + lane] = o;
}

// ---------------------------------------------------------------------------
// Decoder: out = H @ Wdec^T -> [N, 64].
// block=1024 (16 waves); wave handles 4 rows; lane = output channel.
__global__ __launch_bounds__(1024) void decoder_k(
        const float* __restrict__ H, const float* __restrict__ Wdec,
        float* __restrict__ out) {
    __shared__ float WT[HID_C * (OUT_C + 1)];  // WT[k*65 + o] = Wdec[o*128 + k]
    for (int i = threadIdx.x; i < OUT_C * HID_C; i += 1024) {
        int o = i >> 7, k = i & 127;
        WT[k * 65 + o] = Wdec[i];
    }
    __syncthreads();
    int lane = threadIdx.x & 63;
    int wid  = threadIdx.x >> 6;
    int wstride = gridDim.x * 16;
    for (int grp = blockIdx.x * 16 + wid; grp * 4 < N_NODES; grp += wstride) {
        int r0 = grp * 4;
        const float* hp = H + (size_t)r0 * HID_C;
        float a0 = 0, a1 = 0, a2 = 0, a3 = 0;
#pragma unroll 8
        for (int k = 0; k < HID_C; ++k) {
            float w = WT[k * 65 + lane];
            a0 = fmaf(hp[k],             w, a0);
            a1 = fmaf(hp[HID_C + k],     w, a1);
            a2 = fmaf(hp[2 * HID_C + k], w, a2);
            a3 = fmaf(hp[3 * HID_C + k], w, a3);
        }
        out[(size_t)r0 * OUT_C + lane]       = a0;
        out[(size_t)(r0 + 1) * OUT_C + lane] = a1;
        out[(size_t)(r0 + 2) * OUT_C + lane] = a2;
        out[(size_t)(r0 + 3) * OUT_C + lane] = a3;
    }
}

// ---------------------------------------------------------------------------
extern "C" void kernel_launch(void* const* d_in, const int* in_sizes, int n_in,
                              void* d_out, int out_size, void* d_ws, size_t ws_size,
                              hipStream_t stream) {
    const float* x     = (const float*)d_in[0];
    const int*   ei    = (const int*)d_in[1];   // [2, E] int32
    const float* ew    = (const float*)d_in[2];
    const float* Wenc  = (const float*)d_in[3];
    const float* Wdec  = (const float*)d_in[4];
    const float* gamma = (const float*)d_in[5];
    const float* beta  = (const float*)d_in[6];
    float* out = (float*)d_out;

    const int* src = ei;
    const int* dst = ei + N_EDGES;

    char* p = (char*)d_ws;
    auto carve = [&](size_t bytes) -> void* {
        void* r = (void*)p;
        p += (bytes + 255) & ~(size_t)255;
        return r;
    };
    int*  counts  = (int*)carve((N_NODES + 1) * sizeof(int));
    int*  fillpos = (int*)carve((N_NODES + 1) * sizeof(int));
    int*  row_off = (int*)carve((N_NODES + 1) * sizeof(int));
    int2* ep      = (int2*)carve((size_t)N_EDGES * sizeof(int2));
    float* H  = (float*)carve((size_t)N_NODES * HID_C * sizeof(float));
    float* ZA = (float*)carve((size_t)N_NODES * HID_C * sizeof(float));
    float* ZB = (float*)carve((size_t)N_NODES * HID_C * sizeof(float));

    // CSR build (per launch; deterministic work each call)
    hipMemsetAsync(counts, 0, (N_NODES + 1) * sizeof(int), stream);
    count_k<<<(N_EDGES + 255) / 256, 256, 0, stream>>>(dst, counts);
    scan_k<<<1, 1024, 0, stream>>>(counts, row_off, fillpos);
    bucket_k<<<(N_EDGES + 255) / 256, 256, 0, stream>>>(src, dst, ew, fillpos, ep);

    // Encoder
    encoder_k<<<512, 1024, 0, stream>>>(x, Wenc, gamma, beta, H);

    const int node_blocks = (N_NODES + 3) / 4;   // 4 waves (rows) per 256-block
    float* bufs[2] = {ZA, ZB};
    for (int l = 0; l < NLAYERS; ++l) {
        const float* zin = H;                     // x0 = H (layer input)
        for (int k = 0; k < KSTEPS; ++k) {
            float* zout = bufs[k & 1];
            prop_k<<<node_blocks, 256, 0, stream>>>(zin, H, row_off, ep, zout);
            zin = zout;
        }
        gelu_ln_k<<<node_blocks, 256, 0, stream>>>(zin, gamma, beta, H);
    }

    decoder_k<<<512, 1024, 0, stream>>>(H, Wdec, out);
}

// Round 3
// 5176.570 us; speedup vs baseline: 1.1854x; 1.0948x over previous
//
#include <hip/hip_runtime.h>
#include <math.h>

#define N_NODES 100000
#define N_EDGES 1600000
#define IN_C 128
#define HID_C 128
#define OUT_C 64
#define NLAYERS 4
#define KSTEPS 10
#define ALPHA 0.1f
#define LN_EPS 1e-5f

#define SCAN_N (N_NODES + 1)
#define SCAN_BLOCKS ((SCAN_N + 1023) / 1024)     // 98
#define EP_CAP 2400000                            // 1.6M edges + <=7 pad/node

__device__ __forceinline__ float gelu_exact(float x) {
    // jax.nn.gelu(approximate=False) = 0.5*x*(1+erf(x/sqrt(2)))
    return 0.5f * x * (1.0f + erff(x * 0.70710678118654752f));
}

// ---------------------------------------------------------------------------
// CSR build: count in-degree per dst
__global__ void count_k(const int* __restrict__ dst, int* __restrict__ counts) {
    int e = blockIdx.x * blockDim.x + threadIdx.x;
    if (e < N_EDGES) atomicAdd(&counts[dst[e]], 1);
}

// Parallel exclusive scan over PADDED counts (padded to multiple of 8 per node).
// scan1: per-block sums of padded counts
__global__ __launch_bounds__(1024) void scan1_k(const int* __restrict__ counts,
                                                int* __restrict__ bsum) {
    __shared__ int s[1024];
    int i = blockIdx.x * 1024 + threadIdx.x;
    int c = 0;
    if (i < N_NODES) c = (counts[i] + 7) & ~7;     // pad to x8; counts[N_NODES]=0
    s[threadIdx.x] = c;
    __syncthreads();
    for (int off = 512; off; off >>= 1) {
        if (threadIdx.x < off) s[threadIdx.x] += s[threadIdx.x + off];
        __syncthreads();
    }
    if (threadIdx.x == 0) bsum[blockIdx.x] = s[0];
}

// scan2: exclusive scan of the 98 block sums (single small block)
__global__ void scan2_k(int* __restrict__ bsum) {
    __shared__ int s[128];
    int t = threadIdx.x;
    s[t] = (t < SCAN_BLOCKS) ? bsum[t] : 0;
    __syncthreads();
    for (int off = 1; off < 128; off <<= 1) {
        int v = (t >= off) ? s[t - off] : 0;
        __syncthreads();
        s[t] += v;
        __syncthreads();
    }
    if (t < SCAN_BLOCKS) bsum[t] = (t == 0) ? 0 : s[t - 1];
}

// scan3: per-block exclusive scan + block offset -> row_off / fill_pos
__global__ __launch_bounds__(1024) void scan3_k(const int* __restrict__ counts,
                                                const int* __restrict__ bsum,
                                                int* __restrict__ row_off,
                                                int* __restrict__ fill_pos) {
    __shared__ int s[1024];
    int i = blockIdx.x * 1024 + threadIdx.x;
    int c = 0;
    if (i < N_NODES) c = (counts[i] + 7) & ~7;
    s[threadIdx.x] = c;
    __syncthreads();
    for (int off = 1; off < 1024; off <<= 1) {
        int v = (threadIdx.x >= off) ? s[threadIdx.x - off] : 0;
        __syncthreads();
        s[threadIdx.x] += v;
        __syncthreads();
    }
    if (i <= N_NODES) {
        int excl = s[threadIdx.x] - c + bsum[blockIdx.x];
        row_off[i] = excl;
        fill_pos[i] = excl;
    }
}

// Bucket edges by dst; pack (src, (1-alpha)*w) into int2.
// Pad slots (up to next x8) stay (0,0.0f) from the ep memset -> no-op edges.
__global__ void bucket_k(const int* __restrict__ src, const int* __restrict__ dst,
                         const float* __restrict__ w,
                         int* __restrict__ fill_pos, int2* __restrict__ ep) {
    int e = blockIdx.x * blockDim.x + threadIdx.x;
    if (e >= N_EDGES) return;
    int d = dst[e];
    int pos = atomicAdd(&fill_pos[d], 1);
    float ws = (1.0f - ALPHA) * w[e];
    ep[pos] = make_int2(src[e], __float_as_int(ws));
}

// ---------------------------------------------------------------------------
// LN(+gelu) epilogue for one row; lane holds channels (lane, lane+64).
__device__ __forceinline__ void ln_gelu_store(float a0, float a1,
                                              float g0, float g1, float b0, float b1,
                                              float* __restrict__ Hrow, int lane) {
    float sum = a0 + a1;
    for (int off = 32; off; off >>= 1) sum += __shfl_xor(sum, off);
    float mu = sum * (1.0f / 128.0f);
    float d0 = a0 - mu, d1 = a1 - mu;
    float vs = d0 * d0 + d1 * d1;
    for (int off = 32; off; off >>= 1) vs += __shfl_xor(vs, off);
    float inv = rsqrtf(vs * (1.0f / 128.0f) + LN_EPS);
    Hrow[lane]      = gelu_exact(g0 * d0 * inv + b0);
    Hrow[64 + lane] = gelu_exact(g1 * d1 * inv + b1);
}

// Encoder: H = gelu(LN(x @ Wenc^T)).
__global__ __launch_bounds__(1024) void encoder_k(
        const float* __restrict__ x, const float* __restrict__ Wenc,
        const float* __restrict__ gamma, const float* __restrict__ beta,
        float* __restrict__ H) {
    __shared__ float WT[IN_C * (HID_C + 1)];   // WT[k*129 + c] = Wenc[c*128 + k]
    for (int i = threadIdx.x; i < IN_C * HID_C; i += 1024) {
        int c = i >> 7, k = i & 127;
        WT[k * 129 + c] = Wenc[i];
    }
    __syncthreads();
    int lane = threadIdx.x & 63;
    int wid  = threadIdx.x >> 6;               // 0..15
    float g0 = gamma[lane], g1 = gamma[lane + 64];
    float b0 = beta[lane],  b1 = beta[lane + 64];
    int wstride = gridDim.x * 16;
    for (int grp = blockIdx.x * 16 + wid; grp * 4 < N_NODES; grp += wstride) {
        int r0 = grp * 4;
        const float* xp = x + (size_t)r0 * IN_C;
        float a00 = 0, a01 = 0, a10 = 0, a11 = 0;
        float a20 = 0, a21 = 0, a30 = 0, a31 = 0;
#pragma unroll 8
        for (int k = 0; k < IN_C; ++k) {
            float w0 = WT[k * 129 + lane];
            float w1 = WT[k * 129 + 64 + lane];
            float x0k = xp[k];
            float x1k = xp[IN_C + k];
            float x2k = xp[2 * IN_C + k];
            float x3k = xp[3 * IN_C + k];
            a00 = fmaf(x0k, w0, a00); a01 = fmaf(x0k, w1, a01);
            a10 = fmaf(x1k, w0, a10); a11 = fmaf(x1k, w1, a11);
            a20 = fmaf(x2k, w0, a20); a21 = fmaf(x2k, w1, a21);
            a30 = fmaf(x3k, w0, a30); a31 = fmaf(x3k, w1, a31);
        }
        ln_gelu_store(a00, a01, g0, g1, b0, b1, H + (size_t)r0 * HID_C,       lane);
        ln_gelu_store(a10, a11, g0, g1, b0, b1, H + (size_t)(r0 + 1) * HID_C, lane);
        ln_gelu_store(a20, a21, g0, g1, b0, b1, H + (size_t)(r0 + 2) * HID_C, lane);
        ln_gelu_store(a30, a31, g0, g1, b0, b1, H + (size_t)(r0 + 3) * HID_C, lane);
    }
}

// ---------------------------------------------------------------------------
// One APPNP step (pull): zout[n] = alpha*x0[n] + sum_{e into n} w'_e * zin[src_e]
// Wave per node; lane holds channels (2l, 2l+1) as float2.
// Edge params loaded cooperatively (one vector load per 64 edges) and
// shfl-broadcast; padded degree (x8) -> branch-free 8-wide gather groups.
// fuse_ln != 0: apply gelu then LayerNorm before storing (last K-step).
__global__ __launch_bounds__(256) void prop_k(
        const float* __restrict__ zin, const float* __restrict__ x0,
        const int* __restrict__ row_off, const int2* __restrict__ ep,
        float* __restrict__ zout, int fuse_ln,
        const float* __restrict__ gamma, const float* __restrict__ beta) {
    int gw = (blockIdx.x * 256 + threadIdx.x) >> 6;   // node id
    if (gw >= N_NODES) return;
    int lane = threadIdx.x & 63;
    int s0 = row_off[gw];
    int s1 = row_off[gw + 1];                          // padded degree, multiple of 8
    const float2* z2 = (const float2*)zin;
    float2 xv = ((const float2*)x0)[(size_t)gw * 64 + lane];
    float sx = 0.f, sy = 0.f;
    for (int base = s0; base < s1; base += 64) {
        int cnt = min(64, s1 - base);                  // multiple of 8
        int2 p = make_int2(0, 0);
        if (lane < cnt) p = ep[base + lane];
        for (int j = 0; j < cnt; j += 8) {
            int   a0 = __shfl(p.x, j + 0); float w0 = __int_as_float(__shfl(p.y, j + 0));
            int   a1 = __shfl(p.x, j + 1); float w1 = __int_as_float(__shfl(p.y, j + 1));
            int   a2 = __shfl(p.x, j + 2); float w2 = __int_as_float(__shfl(p.y, j + 2));
            int   a3 = __shfl(p.x, j + 3); float w3 = __int_as_float(__shfl(p.y, j + 3));
            int   a4 = __shfl(p.x, j + 4); float w4 = __int_as_float(__shfl(p.y, j + 4));
            int   a5 = __shfl(p.x, j + 5); float w5 = __int_as_float(__shfl(p.y, j + 5));
            int   a6 = __shfl(p.x, j + 6); float w6 = __int_as_float(__shfl(p.y, j + 6));
            int   a7 = __shfl(p.x, j + 7); float w7 = __int_as_float(__shfl(p.y, j + 7));
            float2 v0 = z2[(size_t)a0 * 64 + lane];
            float2 v1 = z2[(size_t)a1 * 64 + lane];
            float2 v2 = z2[(size_t)a2 * 64 + lane];
            float2 v3 = z2[(size_t)a3 * 64 + lane];
            float2 v4 = z2[(size_t)a4 * 64 + lane];
            float2 v5 = z2[(size_t)a5 * 64 + lane];
            float2 v6 = z2[(size_t)a6 * 64 + lane];
            float2 v7 = z2[(size_t)a7 * 64 + lane];
            sx = fmaf(w0, v0.x, sx); sy = fmaf(w0, v0.y, sy);
            sx = fmaf(w1, v1.x, sx); sy = fmaf(w1, v1.y, sy);
            sx = fmaf(w2, v2.x, sx); sy = fmaf(w2, v2.y, sy);
            sx = fmaf(w3, v3.x, sx); sy = fmaf(w3, v3.y, sy);
            sx = fmaf(w4, v4.x, sx); sy = fmaf(w4, v4.y, sy);
            sx = fmaf(w5, v5.x, sx); sy = fmaf(w5, v5.y, sy);
            sx = fmaf(w6, v6.x, sx); sy = fmaf(w6, v6.y, sy);
            sx = fmaf(w7, v7.x, sx); sy = fmaf(w7, v7.y, sy);
        }
    }
    float z0 = fmaf(ALPHA, xv.x, sx);
    float z1 = fmaf(ALPHA, xv.y, sy);
    float2 o;
    if (fuse_ln) {
        // h = gelu(z); H = LN(h) * gamma + beta   (channels (2l, 2l+1))
        float h0 = gelu_exact(z0);
        float h1 = gelu_exact(z1);
        float sum = h0 + h1;
        for (int off = 32; off; off >>= 1) sum += __shfl_xor(sum, off);
        float mu = sum * (1.0f / 128.0f);
        float d0 = h0 - mu, d1 = h1 - mu;
        float vs = d0 * d0 + d1 * d1;
        for (int off = 32; off; off >>= 1) vs += __shfl_xor(vs, off);
        float inv = rsqrtf(vs * (1.0f / 128.0f) + LN_EPS);
        float2 gb = ((const float2*)gamma)[lane];
        float2 bb = ((const float2*)beta)[lane];
        o.x = gb.x * d0 * inv + bb.x;
        o.y = gb.y * d1 * inv + bb.y;
    } else {
        o.x = z0;
        o.y = z1;
    }
    ((float2*)zout)[(size_t)gw * 64 + lane] = o;
}

// ---------------------------------------------------------------------------
// Decoder: out = H @ Wdec^T -> [N, 64].
__global__ __launch_bounds__(1024) void decoder_k(
        const float* __restrict__ H, const float* __restrict__ Wdec,
        float* __restrict__ out) {
    __shared__ float WT[HID_C * (OUT_C + 1)];  // WT[k*65 + o] = Wdec[o*128 + k]
    for (int i = threadIdx.x; i < OUT_C * HID_C; i += 1024) {
        int o = i >> 7, k = i & 127;
        WT[k * 65 + o] = Wdec[i];
    }
    __syncthreads();
    int lane = threadIdx.x & 63;
    int wid  = threadIdx.x >> 6;
    int wstride = gridDim.x * 16;
    for (int grp = blockIdx.x * 16 + wid; grp * 4 < N_NODES; grp += wstride) {
        int r0 = grp * 4;
        const float* hp = H + (size_t)r0 * HID_C;
        float a0 = 0, a1 = 0, a2 = 0, a3 = 0;
#pragma unroll 8
        for (int k = 0; k < HID_C; ++k) {
            float w = WT[k * 65 + lane];
            a0 = fmaf(hp[k],             w, a0);
            a1 = fmaf(hp[HID_C + k],     w, a1);
            a2 = fmaf(hp[2 * HID_C + k], w, a2);
            a3 = fmaf(hp[3 * HID_C + k], w, a3);
        }
        out[(size_t)r0 * OUT_C + lane]       = a0;
        out[(size_t)(r0 + 1) * OUT_C + lane] = a1;
        out[(size_t)(r0 + 2) * OUT_C + lane] = a2;
        out[(size_t)(r0 + 3) * OUT_C + lane] = a3;
    }
}

// ---------------------------------------------------------------------------
extern "C" void kernel_launch(void* const* d_in, const int* in_sizes, int n_in,
                              void* d_out, int out_size, void* d_ws, size_t ws_size,
                              hipStream_t stream) {
    const float* x     = (const float*)d_in[0];
    const int*   ei    = (const int*)d_in[1];   // [2, E] int32
    const float* ew    = (const float*)d_in[2];
    const float* Wenc  = (const float*)d_in[3];
    const float* Wdec  = (const float*)d_in[4];
    const float* gamma = (const float*)d_in[5];
    const float* beta  = (const float*)d_in[6];
    float* out = (float*)d_out;

    const int* src = ei;
    const int* dst = ei + N_EDGES;

    char* p = (char*)d_ws;
    auto carve = [&](size_t bytes) -> void* {
        void* r = (void*)p;
        p += (bytes + 255) & ~(size_t)255;
        return r;
    };
    int*  counts  = (int*)carve(SCAN_N * sizeof(int));
    int*  fillpos = (int*)carve(SCAN_N * sizeof(int));
    int*  row_off = (int*)carve(SCAN_N * sizeof(int));
    int*  bsum    = (int*)carve(SCAN_BLOCKS * sizeof(int));
    int2* ep      = (int2*)carve((size_t)EP_CAP * sizeof(int2));
    float* H  = (float*)carve((size_t)N_NODES * HID_C * sizeof(float));
    float* ZA = (float*)carve((size_t)N_NODES * HID_C * sizeof(float));
    float* ZB = (float*)carve((size_t)N_NODES * HID_C * sizeof(float));

    // CSR build (per launch; deterministic work each call)
    hipMemsetAsync(counts, 0, SCAN_N * sizeof(int), stream);
    hipMemsetAsync(ep, 0, (size_t)EP_CAP * sizeof(int2), stream);  // pads -> (0,0.0f)
    count_k<<<(N_EDGES + 255) / 256, 256, 0, stream>>>(dst, counts);
    scan1_k<<<SCAN_BLOCKS, 1024, 0, stream>>>(counts, bsum);
    scan2_k<<<1, 128, 0, stream>>>(bsum);
    scan3_k<<<SCAN_BLOCKS, 1024, 0, stream>>>(counts, bsum, row_off, fillpos);
    bucket_k<<<(N_EDGES + 255) / 256, 256, 0, stream>>>(src, dst, ew, fillpos, ep);

    // Encoder
    encoder_k<<<512, 1024, 0, stream>>>(x, Wenc, gamma, beta, H);

    const int node_blocks = (N_NODES + 3) / 4;   // 4 waves (nodes) per 256-block
    float* bufs[2] = {ZA, ZB};
    for (int l = 0; l < NLAYERS; ++l) {
        const float* zin = H;                     // x0 = H (layer input)
        for (int k = 0; k < KSTEPS; ++k) {
            int last = (k == KSTEPS - 1);
            float* zout = last ? H : bufs[k & 1]; // fused gelu+LN writes H in place
            prop_k<<<node_blocks, 256, 0, stream>>>(zin, H, row_off, ep, zout,
                                                    last, gamma, beta);
            zin = zout;
        }
    }

    decoder_k<<<512, 1024, 0, stream>>>(H, Wdec, out);
}